// Round 9
// baseline (351.538 us; speedup 1.0000x reference)
//
#include <hip/hip_runtime.h>
#include <math.h>

#define D 128
#define B_SZ 1024
#define KNB 200
#define QAW 136   // qA stride (halves)
#define HAW 264   // HA [h|r] stride (halves)
#define SCW 1028  // Sc stride (f32)
#define PW 1048   // P stride (halves)

typedef _Float16 half8 __attribute__((ext_vector_type(8)));
typedef float floatx4 __attribute__((ext_vector_type(4)));

__device__ __forceinline__ float sigmoid_f(float x) { return 1.f / (1.f + __expf(-x)); }
__device__ __forceinline__ float tanh_fast(float x) { return 1.f - 2.f / (__expf(2.f * x) + 1.f); }

// ---------------------------------------------------------------------------
// Kernel 0: one-time fp16 LSTM weights (split layout):
// w16[0:131072] = w_ih [1024][128]; w16[131072:] = w_hh [1024][256].
// ---------------------------------------------------------------------------
__global__ __launch_bounds__(256) void k_cvtw(
    const float* __restrict__ w_ih, const float* __restrict__ w_hh,
    _Float16* __restrict__ w16)
{
    const int i8 = (blockIdx.x * 256 + threadIdx.x) * 8;
    const float* src = (i8 < 131072) ? (w_ih + i8) : (w_hh + (i8 - 131072));
    float4 v0 = *(const float4*)src;
    float4 v1 = *(const float4*)(src + 4);
    half8 h;
    h[0] = (_Float16)v0.x; h[1] = (_Float16)v0.y; h[2] = (_Float16)v0.z; h[3] = (_Float16)v0.w;
    h[4] = (_Float16)v1.x; h[5] = (_Float16)v1.y; h[6] = (_Float16)v1.z; h[7] = (_Float16)v1.w;
    *(half8*)&w16[i8] = h;
}

// ---------------------------------------------------------------------------
// Kernel 1: gather+sum, GCN linear, support encoder, query gather.
// One block per batch row b, 512 threads. (Known wall: ~1.25 TB/s random.)
// ---------------------------------------------------------------------------
__global__ __launch_bounds__(512) void k_support(
    const int* __restrict__ relations, const int* __restrict__ entities,
    const int* __restrict__ query, const float* __restrict__ emb,
    const float* __restrict__ gcn_w, const float* __restrict__ gcn_b,
    const float* __restrict__ p1_w, const float* __restrict__ p1_b,
    const float* __restrict__ p2_w, const float* __restrict__ p2_b,
    const float* __restrict__ ln_a, const float* __restrict__ ln_b,
    float* __restrict__ sg, _Float16* __restrict__ sgH, _Float16* __restrict__ sgT,
    _Float16* __restrict__ qbH)
{
    __shared__ int idxs[2 * KNB];
    __shared__ __align__(16) float part[16][132];
    __shared__ __align__(16) float S[2 * D];
    __shared__ __align__(16) float sup[D];
    __shared__ __align__(16) float hid[2 * D];
    __shared__ __align__(16) float zv[D];
    __shared__ float red2[2];

    const int b = blockIdx.x;
    const int t = threadIdx.x;

    if (t < KNB) idxs[t] = relations[b * KNB + t];
    else if (t < 2 * KNB) idxs[t] = entities[b * KNB + (t - KNB)];
    __syncthreads();

    {
        const int g = t >> 5, c4 = (t & 31) * 4;
        const int* mi = &idxs[(g >> 3) * KNB];
        float4 a4 = make_float4(0.f, 0.f, 0.f, 0.f);
        #pragma unroll 5
        for (int k = (g & 7); k < KNB; k += 8) {
            float4 v = *(const float4*)&emb[(size_t)mi[k] * D + c4];
            a4.x += v.x; a4.y += v.y; a4.z += v.z; a4.w += v.w;
        }
        *(float4*)&part[g][c4] = a4;
    }
    __syncthreads();
    if (t < 2 * D) {
        const int half = t >> 7, c = t & 127;
        float s = 0.f;
        #pragma unroll
        for (int j = 0; j < 8; ++j) s += part[half * 8 + j][c];
        S[t] = s;
    }
    __syncthreads();

    if (t < D) {
        const float4* w4 = (const float4*)(gcn_w + t * 2 * D);
        float dot = 0.f;
        #pragma unroll 8
        for (int f = 0; f < 2 * D / 4; ++f) {
            float4 w = w4[f];
            float4 s = *(const float4*)&S[f * 4];
            dot += w.x * s.x + w.y * s.y + w.z * s.z + w.w * s.w;
        }
        float v = (dot + 200.f * gcn_b[t]) * (1.f / 1024.f);  // num_neighbors = B = 1024
        sup[t] = tanhf(v);
    }
    __syncthreads();

    if (t < 2 * D) {
        const float4* w4 = (const float4*)(p1_w + t * D);
        float dot = 0.f;
        #pragma unroll 8
        for (int f = 0; f < D / 4; ++f) {
            float4 w = w4[f];
            float4 s = *(const float4*)&sup[f * 4];
            dot += w.x * s.x + w.y * s.y + w.z * s.z + w.w * s.w;
        }
        float h = dot + p1_b[t];
        hid[t] = h > 0.f ? h : 0.f;
    }
    __syncthreads();

    if (t < D) {
        const float4* w4 = (const float4*)(p2_w + t * 2 * D);
        float dot = 0.f;
        #pragma unroll 8
        for (int f = 0; f < 2 * D / 4; ++f) {
            float4 w = w4[f];
            float4 s = *(const float4*)&hid[f * 4];
            dot += w.x * s.x + w.y * s.y + w.z * s.z + w.w * s.w;
        }
        zv[t] = dot + p2_b[t] + sup[t];
    }
    __syncthreads();

    if (t < 64) {
        float x0 = zv[t], x1 = zv[t + 64];
        float s = x0 + x1;
        for (int off = 32; off; off >>= 1) s += __shfl_down(s, off);
        float mu = __shfl(s, 0) * (1.f / 128.f);
        float d0 = x0 - mu, d1 = x1 - mu;
        float v = d0 * d0 + d1 * d1;
        for (int off = 32; off; off >>= 1) v += __shfl_down(v, off);
        v = __shfl(v, 0);
        if (t == 0) { red2[0] = mu; red2[1] = sqrtf(v * (1.f / 127.f)); }
    }
    __syncthreads();
    if (t < D) {
        float mu = red2[0], sigma = red2[1];
        float val = (zv[t] - mu) / (sigma + 1e-3f) * ln_a[t] + ln_b[t];
        sg[b * D + t] = val;
        sgH[b * D + t] = (_Float16)val;
        sgT[t * B_SZ + b] = (_Float16)val;
        qbH[b * D + t] = (_Float16)emb[(size_t)query[b] * D + t];
    }
}

// ---------------------------------------------------------------------------
// Kernel 2: fused LSTM step. 64 blocks x 16 rows, 1024 threads (16 waves).
// first=1: compute gq = q@w_ih^T (+bias, stored to gqB), step-0 pointwise
// (c=0) -> h0 in LDS. Then: attn(h) -> r (LDS) -> gates (gq + [h|r]@w_hh^T)
// -> pointwise -> h',c' (global for next step). last=1: cosine epilogue.
// Gate-column trick: MFMA output col m -> (gate=m&3, unit=m>>2), so the
// pointwise gathers a unit's 4 gates with quad-local __shfl (no LDS).
// ---------------------------------------------------------------------------
__global__ __launch_bounds__(1024) void k_step(
    const _Float16* __restrict__ qbH, const _Float16* __restrict__ sgH,
    const _Float16* __restrict__ sgT, const float* __restrict__ sg,
    const _Float16* __restrict__ w16, const float* __restrict__ b_ih,
    const float* __restrict__ b_hh, float* __restrict__ gqB,
    float* __restrict__ cbuf, _Float16* __restrict__ hH,
    float* __restrict__ out, int first, int last)
{
    __shared__ _Float16 qA[16 * QAW];
    __shared__ _Float16 HA[16 * HAW];     // [16][264]: 0:128 h | 128:256 r
    __shared__ float    Sc[16 * SCW];
    __shared__ _Float16 P[16 * PW];
    __shared__ float    rpar[2][16][132];
    __shared__ float    sinv[16];
    __shared__ float    hsave[16][132];

    const int t = threadIdx.x;
    const int wv = t >> 6, lane = t & 63;
    const int m = lane & 15, quad = lane >> 4;
    const int b0 = blockIdx.x * 16;
    const int u0 = wv * 16;
    const int gg = m & 3;
    const int base = lane & 60;  // shuffle base: same quad, same unit group

    // stage q rows; stage h rows (steps 2,3)
    if (t < 256) {
        const int row = t >> 4, c = (t & 15) * 8;
        *(half8*)&qA[row * QAW + c] = *(const half8*)&qbH[(b0 + row) * D + c];
    }
    if (!first && t >= 256 && t < 512) {
        const int idx = t - 256;
        const int row = idx >> 4, c = (idx & 15) * 8;
        *(half8*)&HA[row * HAW + c] = *(const half8*)&hH[(b0 + row) * D + c];
    }

    int ucol[4], wrow[4];
    #pragma unroll
    for (int j = 0; j < 4; ++j) { ucol[j] = u0 + j * 4 + (m >> 2); wrow[j] = gg * 256 + ucol[j]; }

    float gqb[4][4];   // biased q-gates, [sub][rr]
    float creg[4][4];  // carried cell state
    if (!first) {
        #pragma unroll
        for (int j = 0; j < 4; ++j)
            #pragma unroll
            for (int rr = 0; rr < 4; ++rr) {
                const int b = b0 + quad * 4 + rr;
                gqb[j][rr] = gqB[(size_t)b * 1024 + wrow[j]];
                creg[j][rr] = cbuf[b * 256 + ucol[j]];
            }
    }
    __syncthreads();

    // q residual values for the pointwise (rows quad*4+rr, unit ucol[j])
    float qvr[4][4];
    if (wv < 8) {
        #pragma unroll
        for (int j = 0; j < 4; ++j)
            #pragma unroll
            for (int rr = 0; rr < 4; ++rr)
                qvr[j][rr] = (float)qA[(quad * 4 + rr) * QAW + ucol[j]];
    }

    if (first) {
        // ---- gq = q @ w_ih^T (K=128), cols = (gate, unit) interleaved
        floatx4 a0[4];
        #pragma unroll
        for (int j = 0; j < 4; ++j)
            #pragma unroll
            for (int z = 0; z < 4; ++z) a0[j][z] = 0.f;
        #pragma unroll
        for (int ks = 0; ks < 4; ++ks) {
            half8 a = *(const half8*)&qA[m * QAW + ks * 32 + quad * 8];
            #pragma unroll
            for (int j = 0; j < 4; ++j) {
                half8 bf = *(const half8*)&w16[wrow[j] * D + ks * 32 + quad * 8];
                a0[j] = __builtin_amdgcn_mfma_f32_16x16x32_f16(a, bf, a0[j], 0, 0, 0);
            }
        }
        #pragma unroll
        for (int j = 0; j < 4; ++j) {
            const float bv = b_ih[wrow[j]] + b_hh[wrow[j]];
            #pragma unroll
            for (int rr = 0; rr < 4; ++rr) {
                gqb[j][rr] = a0[j][rr] + bv;
                gqB[(size_t)(b0 + quad * 4 + rr) * 1024 + wrow[j]] = gqb[j][rr];
            }
        }
        // ---- step-0 pointwise (c = 0) -> h0 into HA
        #pragma unroll
        for (int j = 0; j < 4; ++j)
            #pragma unroll
            for (int rr = 0; rr < 4; ++rr) {
                float v = gqb[j][rr];
                float gi = __shfl(v, base + 0);
                float ggt = __shfl(v, base + 2);
                float go = __shfl(v, base + 3);
                float cn = sigmoid_f(gi) * tanh_fast(ggt);
                creg[j][rr] = cn;
                if (wv < 8) {
                    float ho = qvr[j][rr] + sigmoid_f(go) * tanh_fast(cn);
                    if (gg == 0) HA[(quad * 4 + rr) * HAW + ucol[j]] = (_Float16)ho;
                }
            }
    }
    __syncthreads();  // h ready in HA

    // ================= attention =================
    // scores: wave wv -> j-tiles wv*4..+3
    {
        floatx4 s4[4];
        #pragma unroll
        for (int i = 0; i < 4; ++i)
            #pragma unroll
            for (int z = 0; z < 4; ++z) s4[i][z] = 0.f;
        #pragma unroll
        for (int ks = 0; ks < 4; ++ks) {
            half8 a = *(const half8*)&HA[m * HAW + ks * 32 + quad * 8];
            #pragma unroll
            for (int i = 0; i < 4; ++i) {
                const int j0 = (wv * 4 + i) * 16;
                half8 bf = *(const half8*)&sgH[(j0 + m) * D + ks * 32 + quad * 8];
                s4[i] = __builtin_amdgcn_mfma_f32_16x16x32_f16(a, bf, s4[i], 0, 0, 0);
            }
        }
        #pragma unroll
        for (int i = 0; i < 4; ++i) {
            const int j0 = (wv * 4 + i) * 16;
            #pragma unroll
            for (int rr = 0; rr < 4; ++rr)
                Sc[(quad * 4 + rr) * SCW + j0 + m] = s4[i][rr];
        }
    }
    __syncthreads();
    // softmax: wave wv owns row wv
    {
        const int row = wv;
        float vals[16];
        float mm = -1e30f;
        #pragma unroll
        for (int j = 0; j < 16; ++j) {
            vals[j] = Sc[row * SCW + lane + j * 64];
            mm = fmaxf(mm, vals[j]);
        }
        #pragma unroll
        for (int off = 32; off; off >>= 1) mm = fmaxf(mm, __shfl_down(mm, off));
        mm = __shfl(mm, 0);
        float ss = 0.f;
        #pragma unroll
        for (int j = 0; j < 16; ++j) {
            float e = __expf(vals[j] - mm);
            P[row * PW + lane + j * 64] = (_Float16)e;
            ss += e;
        }
        #pragma unroll
        for (int off = 32; off; off >>= 1) ss += __shfl_down(ss, off);
        if (lane == 0) sinv[row] = 1.f / ss;
    }
    __syncthreads();
    // r partials: wave -> (n-tile = wv&7, K-half = wv>>3)
    {
        const int nt = wv & 7, kh = wv >> 3;
        floatx4 a3;
        #pragma unroll
        for (int z = 0; z < 4; ++z) a3[z] = 0.f;
        #pragma unroll
        for (int ks = 0; ks < 16; ++ks) {
            const int kk = kh * 16 + ks;
            half8 a = *(const half8*)&P[m * PW + kk * 32 + quad * 8];
            half8 bf = *(const half8*)&sgT[(nt * 16 + m) * B_SZ + kk * 32 + quad * 8];
            a3 = __builtin_amdgcn_mfma_f32_16x16x32_f16(a, bf, a3, 0, 0, 0);
        }
        #pragma unroll
        for (int rr = 0; rr < 4; ++rr)
            rpar[kh][quad * 4 + rr][nt * 16 + m] = a3[rr];
    }
    __syncthreads();
    // combine + scale -> r-slice of HA
    for (int e = t; e < 2048; e += 1024) {
        const int row = e >> 7, col = e & 127;
        float v = (rpar[0][row][col] + rpar[1][row][col]) * sinv[row];
        HA[row * HAW + 128 + col] = (_Float16)v;
    }
    __syncthreads();

    // ================= gates (K=256 over [h|r]) =================
    {
        floatx4 ac[4];
        #pragma unroll
        for (int j = 0; j < 4; ++j)
            #pragma unroll
            for (int rr = 0; rr < 4; ++rr) ac[j][rr] = gqb[j][rr];
        #pragma unroll
        for (int ks = 0; ks < 8; ++ks) {
            half8 a = *(const half8*)&HA[m * HAW + ks * 32 + quad * 8];
            #pragma unroll
            for (int j = 0; j < 4; ++j) {
                half8 bf = *(const half8*)&w16[131072 + wrow[j] * 256 + ks * 32 + quad * 8];
                ac[j] = __builtin_amdgcn_mfma_f32_16x16x32_f16(a, bf, ac[j], 0, 0, 0);
            }
        }
        // pointwise
        #pragma unroll
        for (int j = 0; j < 4; ++j)
            #pragma unroll
            for (int rr = 0; rr < 4; ++rr) {
                float v = ac[j][rr];
                float gi = __shfl(v, base + 0);
                float gf = __shfl(v, base + 1);
                float ggt = __shfl(v, base + 2);
                float go = __shfl(v, base + 3);
                float cn = sigmoid_f(gf) * creg[j][rr] + sigmoid_f(gi) * tanh_fast(ggt);
                creg[j][rr] = cn;
                const int b = b0 + quad * 4 + rr;
                if (!last && gg == 0) cbuf[b * 256 + ucol[j]] = cn;
                if (wv < 8) {
                    float ho = qvr[j][rr] + sigmoid_f(go) * tanh_fast(cn);
                    if (gg == 0) {
                        if (!last) hH[b * D + ucol[j]] = (_Float16)ho;
                        else       hsave[quad * 4 + rr][ucol[j]] = ho;
                    }
                }
            }
    }

    // ================= cosine epilogue (last step) =================
    if (last) {
        __syncthreads();
        if (t < 64) {
            const int row = t & 15, part = t >> 4;
            float cr = 0.f, n1 = 0.f, n2 = 0.f;
            #pragma unroll 8
            for (int j = 0; j < 32; ++j) {
                const int c = part * 32 + j;
                float h = hsave[row][c];
                float s = sg[(b0 + row) * D + c];
                cr += h * s; n1 += h * h; n2 += s * s;
            }
            cr += __shfl_down(cr, 16); n1 += __shfl_down(n1, 16); n2 += __shfl_down(n2, 16);
            cr += __shfl_down(cr, 32); n1 += __shfl_down(n1, 32); n2 += __shfl_down(n2, 32);
            if (t < 16) out[b0 + row] = cr / sqrtf(n1 * n2);
        }
    }
}

// ---------------------------------------------------------------------------
extern "C" void kernel_launch(void* const* d_in, const int* in_sizes, int n_in,
                              void* d_out, int out_size, void* d_ws, size_t ws_size,
                              hipStream_t stream)
{
    const int*   relations = (const int*)d_in[0];
    const int*   entities  = (const int*)d_in[1];
    const int*   query     = (const int*)d_in[2];
    const float* emb       = (const float*)d_in[3];
    const float* gcn_w     = (const float*)d_in[4];
    const float* gcn_b     = (const float*)d_in[5];
    const float* p1_w      = (const float*)d_in[6];
    const float* p1_b      = (const float*)d_in[7];
    const float* p2_w      = (const float*)d_in[8];
    const float* p2_b      = (const float*)d_in[9];
    const float* ln_a      = (const float*)d_in[10];
    const float* ln_b      = (const float*)d_in[11];
    const float* w_ih      = (const float*)d_in[12];
    const float* w_hh      = (const float*)d_in[13];
    const float* b_ih      = (const float*)d_in[14];
    const float* b_hh      = (const float*)d_in[15];

    // Workspace (float-slot offsets)
    float* ws = (float*)d_ws;
    float*     sg   = ws;                          // 131072
    _Float16*  sgH  = (_Float16*)(ws + 131072);    // 65536 slots
    _Float16*  sgT  = (_Float16*)(ws + 196608);    // 65536
    _Float16*  qbH  = (_Float16*)(ws + 262144);    // 65536
    _Float16*  hH   = (_Float16*)(ws + 327680);    // 65536
    float*     cb   = ws + 393216;                 // 262144
    float*     gqB  = ws + 655360;                 // 1048576
    _Float16*  w16  = (_Float16*)(ws + 1703936);   // 196608
    // end: 1900544 floats = 7.6 MB

    k_cvtw<<<dim3(192), dim3(256), 0, stream>>>(w_ih, w_hh, w16);
    k_support<<<dim3(B_SZ), dim3(512), 0, stream>>>(
        relations, entities, query, emb, gcn_w, gcn_b,
        p1_w, p1_b, p2_w, p2_b, ln_a, ln_b, sg, sgH, sgT, qbH);

    // step 1 (gq + pw0 + attn + gates), step 2, step 3 (+cosine)
    k_step<<<dim3(64), dim3(1024), 0, stream>>>(
        qbH, sgH, sgT, sg, w16, b_ih, b_hh, gqB, cb, hH, (float*)d_out, 1, 0);
    k_step<<<dim3(64), dim3(1024), 0, stream>>>(
        qbH, sgH, sgT, sg, w16, b_ih, b_hh, gqB, cb, hH, (float*)d_out, 0, 0);
    k_step<<<dim3(64), dim3(1024), 0, stream>>>(
        qbH, sgH, sgT, sg, w16, b_ih, b_hh, gqB, cb, hH, (float*)d_out, 0, 1);
}